// Round 4
// baseline (311.504 us; speedup 1.0000x reference)
//
#include <hip/hip_runtime.h>
#include <stdint.h>

// Problem dims (fixed by reference setup_inputs)
#define M_DIM 16384
#define N_DIM 2048
#define K_DIM 2048

// GEMM geometry: 256x256 tile, BK=64 (i8), 8 waves (2M x 4N), 4-deep LDS pipe
#define BM 256
#define BN 256
#define BK 64
#define NT (K_DIM / BK)                  // 32 K-tiles
#define TILE_A_BYTES (BM * BK)           // 16384
#define TILE_B_BYTES (BN * BK)           // 16384
#define BUF_BYTES (TILE_A_BYTES + TILE_B_BYTES)   // 32768
#define SMEM_BYTES (4 * BUF_BYTES)       // 131072 (4-deep)

typedef int v4i __attribute__((ext_vector_type(4)));

// ---------------------------------------------------------------------------
// Kernel 0: pack widened int32 weights -> int8
// ---------------------------------------------------------------------------
__global__ __launch_bounds__(256) void pack_w_kernel(const int* __restrict__ w32,
                                                     int8_t* __restrict__ w8) {
    const int i = (blockIdx.x * 256 + threadIdx.x) * 8;
    const int4 a = *reinterpret_cast<const int4*>(w32 + i);
    const int4 b = *reinterpret_cast<const int4*>(w32 + i + 4);
    uint32_t lo = (a.x & 255) | ((a.y & 255) << 8) | ((a.z & 255) << 16) | ((uint32_t)(a.w & 255) << 24);
    uint32_t hi = (b.x & 255) | ((b.y & 255) << 8) | ((b.z & 255) << 16) | ((uint32_t)(b.w & 255) << 24);
    int2 pk;
    pk.x = (int)lo;
    pk.y = (int)hi;
    *reinterpret_cast<int2*>(w8 + i) = pk;
}

// ---------------------------------------------------------------------------
// Kernel 1: per-token symmetric int8 quantization — wave-per-row.
// 4 waves/block = 4 rows/block; each lane: 8x float4 dense (16B/lane stride),
// shfl-only reduce (no LDS, no barrier), 8x u32 dense packed stores.
// ---------------------------------------------------------------------------
__global__ __launch_bounds__(256) void quant_kernel(const float* __restrict__ x,
                                                    int8_t* __restrict__ q,
                                                    float* __restrict__ a_s) {
    const int lane = threadIdx.x & 63;
    const int wid = threadIdx.x >> 6;
    const int row = blockIdx.x * 4 + wid;

    const float4* xv = reinterpret_cast<const float4*>(x + (size_t)row * K_DIM);
    float4 v[8];
    #pragma unroll
    for (int j = 0; j < 8; ++j) v[j] = xv[lane + 64 * j];

    float m = 0.0f;
    #pragma unroll
    for (int j = 0; j < 8; ++j) {
        m = fmaxf(m, fmaxf(fmaxf(fabsf(v[j].x), fabsf(v[j].y)),
                           fmaxf(fabsf(v[j].z), fabsf(v[j].w))));
    }
    #pragma unroll
    for (int off = 32; off > 0; off >>= 1)
        m = fmaxf(m, __shfl_xor(m, off));
    const float mag = m;

    const float inv = (mag == 0.0f) ? 1.0f : (127.0f / mag);

    uint32_t* qo = reinterpret_cast<uint32_t*>(q + (size_t)row * K_DIM);
    #pragma unroll
    for (int j = 0; j < 8; ++j) {
        float e[4] = {v[j].x, v[j].y, v[j].z, v[j].w};
        uint32_t pk = 0;
        #pragma unroll
        for (int c = 0; c < 4; ++c) {
            float d = e[c] * inv;
            d = fminf(fmaxf(d, -128.0f), 127.0f);
            int qi = (int)rintf(d);
            pk |= ((uint32_t)(qi & 255)) << (8 * c);
        }
        qo[lane + 64 * j] = pk;
    }

    if (lane == 0) a_s[row] = (mag == 0.0f) ? 1.0f : (mag / 127.0f);
}

// ---------------------------------------------------------------------------
// Kernel 2: int8 GEMM, 256x256 tile, 4-deep pipeline, 2-sub-phase interleave
// (T3+T4): per K-iter two {ds_read subtile + stage-issue -> barrier -> MFMA
// quadrant -> barrier} phases; counted vmcnt (never 0 mid-loop); T2 swizzle
// (conflict-free, verified round 3); T5 setprio around MFMA clusters.
// ---------------------------------------------------------------------------
__global__ __launch_bounds__(512, 2) void gemm_i8_kernel(
    const int8_t* __restrict__ A,    // [M, K]
    const int8_t* __restrict__ W,    // [N, K]
    const float* __restrict__ a_s,   // [M]
    const float* __restrict__ w_s,   // [N]
    float* __restrict__ out)         // [M, N]
{
    extern __shared__ int8_t smem[];

    const int t = threadIdx.x;
    const int lane = t & 63;
    const int wid = t >> 6;      // 0..7
    const int wr = wid >> 2;     // 0..1  (M half)
    const int wc = wid & 3;      // 0..3  (N quarter)

    // XCD-aware bijective swizzle (nwg = 512, divisible by 8)
    const int bid = blockIdx.x;
    const int sbid = (bid & 7) * (gridDim.x >> 3) + (bid >> 3);
    const int bm = sbid >> 3;    // 64 M-tiles
    const int bn = sbid & 7;     // 8 N-tiles

    const int8_t* aSrc = A + (size_t)(bm * BM) * K_DIM;
    const int8_t* bSrc = W + (size_t)(bn * BN) * K_DIM;

    // staging: tile = 256 rows x 64 B = 1024 x 16B chunks; thread covers f and f+512
    const int f0 = t, f1 = t + 512;
    const int r0 = f0 >> 2, u0 = f0 & 3;
    const int r1 = f1 >> 2, u1 = f1 & 3;
    const size_t gOff0 = (size_t)r0 * K_DIM + (size_t)((u0 ^ ((r0 >> 1) & 3)) << 4);
    const size_t gOff1 = (size_t)r1 * K_DIM + (size_t)((u1 ^ ((r1 >> 1) & 3)) << 4);

    #define STAGE_A(tile)                                                                   \
    do {                                                                                    \
        int8_t* base_ = smem + ((tile) & 3) * BUF_BYTES;                                    \
        const int k0_ = (tile) * BK;                                                        \
        __builtin_amdgcn_global_load_lds(                                                   \
            (const __attribute__((address_space(1))) void*)(aSrc + k0_ + gOff0),            \
            (__attribute__((address_space(3))) void*)(base_ + f0 * 16), 16, 0, 0);          \
        __builtin_amdgcn_global_load_lds(                                                   \
            (const __attribute__((address_space(1))) void*)(aSrc + k0_ + gOff1),            \
            (__attribute__((address_space(3))) void*)(base_ + f1 * 16), 16, 0, 0);          \
    } while (0)

    #define STAGE_B(tile)                                                                   \
    do {                                                                                    \
        int8_t* base_ = smem + ((tile) & 3) * BUF_BYTES + TILE_A_BYTES;                     \
        const int k0_ = (tile) * BK;                                                        \
        __builtin_amdgcn_global_load_lds(                                                   \
            (const __attribute__((address_space(1))) void*)(bSrc + k0_ + gOff0),            \
            (__attribute__((address_space(3))) void*)(base_ + f0 * 16), 16, 0, 0);          \
        __builtin_amdgcn_global_load_lds(                                                   \
            (const __attribute__((address_space(1))) void*)(bSrc + k0_ + gOff1),            \
            (__attribute__((address_space(3))) void*)(base_ + f1 * 16), 16, 0, 0);          \
    } while (0)

    // fragment read addressing (swizzled, verified conflict-free round 3)
    const int frow = lane & 15;
    const int fc = lane >> 4;                       // 16B k-chunk 0..3
    const int rA = wr * 128 + frow;                 // + mf*16
    const int rB = wc * 64 + frow;                  // + nf*16
    const int aOff = rA * 64 + ((((rA >> 1) & 3) ^ fc) << 4);   // +16 rows = +1024B, swz invariant
    const int bOff = rB * 64 + ((((rB >> 1) & 3) ^ fc) << 4);

    v4i acc[8][4] = {};

    STAGE_A(0); STAGE_B(0);
    STAGE_A(1); STAGE_B(1);
    STAGE_A(2); STAGE_B(2);
    asm volatile("s_waitcnt vmcnt(8)" ::: "memory");   // tile 0 landed
    __builtin_amdgcn_s_barrier();
    asm volatile("" ::: "memory");

    for (int tt = 0; tt < NT; ++tt) {
        const int8_t* Ab = smem + (tt & 3) * BUF_BYTES;
        const int8_t* Bb = Ab + TILE_A_BYTES;
        const bool pf = (tt + 3 < NT);

        // ---------------- phase 0: A-half mh=0 + all B, stage A(t+3) --------
        v4i af0[4], bf[4];
        #pragma unroll
        for (int mf = 0; mf < 4; ++mf)
            af0[mf] = *(const v4i*)(Ab + aOff + mf * 1024);
        #pragma unroll
        for (int nf = 0; nf < 4; ++nf)
            bf[nf] = *(const v4i*)(Bb + bOff + nf * 1024);
        if (pf) STAGE_A(tt + 3);

        asm volatile("" ::: "memory");
        __builtin_amdgcn_s_barrier();
        asm volatile("" ::: "memory");

        __builtin_amdgcn_s_setprio(1);
        #pragma unroll
        for (int mf = 0; mf < 4; ++mf)
            #pragma unroll
            for (int nf = 0; nf < 4; ++nf)
                acc[mf][nf] = __builtin_amdgcn_mfma_i32_16x16x64_i8(
                    af0[mf], bf[nf], acc[mf][nf], 0, 0, 0);
        __builtin_amdgcn_s_setprio(0);

        asm volatile("" ::: "memory");
        __builtin_amdgcn_s_barrier();
        asm volatile("" ::: "memory");

        // ---------------- phase 1: A-half mh=1, stage B(t+3), counted vmcnt -
        v4i af1[4];
        #pragma unroll
        for (int mf = 0; mf < 4; ++mf)
            af1[mf] = *(const v4i*)(Ab + aOff + 4096 + mf * 1024);
        if (pf) STAGE_B(tt + 3);

        if (tt < NT - 1) {
            // guarantee tile tt+1 fully landed before next iter reads it;
            // leave the 8 newest loads (tiles tt+2, tt+3) in flight.
            if (tt < NT - 3)      asm volatile("s_waitcnt vmcnt(8)" ::: "memory");
            else if (tt < NT - 2) asm volatile("s_waitcnt vmcnt(4)" ::: "memory");
            else                  asm volatile("s_waitcnt vmcnt(0)" ::: "memory");
        }
        __builtin_amdgcn_s_barrier();
        asm volatile("" ::: "memory");

        __builtin_amdgcn_s_setprio(1);
        #pragma unroll
        for (int mf = 0; mf < 4; ++mf)
            #pragma unroll
            for (int nf = 0; nf < 4; ++nf)
                acc[mf + 4][nf] = __builtin_amdgcn_mfma_i32_16x16x64_i8(
                    af1[mf], bf[nf], acc[mf + 4][nf], 0, 0, 0);
        __builtin_amdgcn_s_setprio(0);

        asm volatile("" ::: "memory");
        __builtin_amdgcn_s_barrier();
        asm volatile("" ::: "memory");
    }
    #undef STAGE_A
    #undef STAGE_B

    // epilogue: dequant + store. C/D layout: col=lane&15, row=(lane>>4)*4+j [m89]
    const int row0 = bm * BM + wr * 128;
    const int col0 = bn * BN + wc * 64;
    #pragma unroll
    for (int mf = 0; mf < 8; ++mf) {
        const int rbase = row0 + mf * 16 + (lane >> 4) * 4;
        #pragma unroll
        for (int nf = 0; nf < 4; ++nf) {
            const int c = col0 + nf * 16 + (lane & 15);
            const float ws = w_s[c];
            #pragma unroll
            for (int j = 0; j < 4; ++j) {
                const int r = rbase + j;
                out[(size_t)r * N_DIM + c] = ((float)acc[mf][nf][j] * a_s[r]) * ws;
            }
        }
    }
}

// ---------------------------------------------------------------------------
extern "C" void kernel_launch(void* const* d_in, const int* in_sizes, int n_in,
                              void* d_out, int out_size, void* d_ws, size_t ws_size,
                              hipStream_t stream) {
    const float* x = (const float*)d_in[0];
    const int* w32 = (const int*)d_in[1];       // int8 widened to int32 by harness
    const float* wscale = (const float*)d_in[2];
    float* out = (float*)d_out;

    // workspace layout: [ q int8 M*K | a_s f32 M | w8 int8 N*K ]
    int8_t* q = (int8_t*)d_ws;
    float* a_s = (float*)((char*)d_ws + (size_t)M_DIM * K_DIM);
    int8_t* w8 = (int8_t*)((char*)d_ws + (size_t)M_DIM * K_DIM + (size_t)M_DIM * 4);

    static int smem_set = 0;
    if (!smem_set) {
        hipFuncSetAttribute(reinterpret_cast<const void*>(&gemm_i8_kernel),
                            hipFuncAttributeMaxDynamicSharedMemorySize, SMEM_BYTES);
        smem_set = 1;
    }

    pack_w_kernel<<<(N_DIM * K_DIM) / (256 * 8), 256, 0, stream>>>(w32, w8);
    quant_kernel<<<M_DIM / 4, 256, 0, stream>>>(x, q, a_s);

    const int grid = (M_DIM / BM) * (N_DIM / BN);   // 64 * 8 = 512
    gemm_i8_kernel<<<grid, 512, SMEM_BYTES, stream>>>(q, w8, a_s, wscale, out);
}

// Round 5
// 306.164 us; speedup vs baseline: 1.0174x; 1.0174x over previous
//
#include <hip/hip_runtime.h>
#include <stdint.h>

// Problem dims (fixed by reference setup_inputs)
#define M_DIM 16384
#define N_DIM 2048
#define K_DIM 2048

// GEMM geometry: 256x128 tile, BK=64, 8 waves (4M x 2N, wave=64x64),
// 2-deep LDS (48 KB) -> 2 blocks/CU for cross-block MFMA/LDS overlap.
#define BM 256
#define BN 128
#define BK 64
#define NT (K_DIM / BK)                  // 32 K-tiles
#define TILE_A_BYTES (BM * BK)           // 16384
#define TILE_B_BYTES (BN * BK)           // 8192
#define BUF_BYTES (TILE_A_BYTES + TILE_B_BYTES)   // 24576
// 2 buffers = 49152 B static LDS

typedef int v4i __attribute__((ext_vector_type(4)));

// ---------------------------------------------------------------------------
// Kernel 0: pack widened int32 weights -> int8
// ---------------------------------------------------------------------------
__global__ __launch_bounds__(256) void pack_w_kernel(const int* __restrict__ w32,
                                                     int8_t* __restrict__ w8) {
    const int i = (blockIdx.x * 256 + threadIdx.x) * 8;
    const int4 a = *reinterpret_cast<const int4*>(w32 + i);
    const int4 b = *reinterpret_cast<const int4*>(w32 + i + 4);
    uint32_t lo = (a.x & 255) | ((a.y & 255) << 8) | ((a.z & 255) << 16) | ((uint32_t)(a.w & 255) << 24);
    uint32_t hi = (b.x & 255) | ((b.y & 255) << 8) | ((b.z & 255) << 16) | ((uint32_t)(b.w & 255) << 24);
    int2 pk;
    pk.x = (int)lo;
    pk.y = (int)hi;
    *reinterpret_cast<int2*>(w8 + i) = pk;
}

// ---------------------------------------------------------------------------
// Kernel 1: per-token symmetric int8 quantization — wave-per-row.
// ---------------------------------------------------------------------------
__global__ __launch_bounds__(256) void quant_kernel(const float* __restrict__ x,
                                                    int8_t* __restrict__ q,
                                                    float* __restrict__ a_s) {
    const int lane = threadIdx.x & 63;
    const int wid = threadIdx.x >> 6;
    const int row = blockIdx.x * 4 + wid;

    const float4* xv = reinterpret_cast<const float4*>(x + (size_t)row * K_DIM);
    float4 v[8];
    #pragma unroll
    for (int j = 0; j < 8; ++j) v[j] = xv[lane + 64 * j];

    float m = 0.0f;
    #pragma unroll
    for (int j = 0; j < 8; ++j) {
        m = fmaxf(m, fmaxf(fmaxf(fabsf(v[j].x), fabsf(v[j].y)),
                           fmaxf(fabsf(v[j].z), fabsf(v[j].w))));
    }
    #pragma unroll
    for (int off = 32; off > 0; off >>= 1)
        m = fmaxf(m, __shfl_xor(m, off));
    const float mag = m;

    const float inv = (mag == 0.0f) ? 1.0f : (127.0f / mag);

    uint32_t* qo = reinterpret_cast<uint32_t*>(q + (size_t)row * K_DIM);
    #pragma unroll
    for (int j = 0; j < 8; ++j) {
        float e[4] = {v[j].x, v[j].y, v[j].z, v[j].w};
        uint32_t pk = 0;
        #pragma unroll
        for (int c = 0; c < 4; ++c) {
            float d = e[c] * inv;
            d = fminf(fmaxf(d, -128.0f), 127.0f);
            int qi = (int)rintf(d);
            pk |= ((uint32_t)(qi & 255)) << (8 * c);
        }
        qo[lane + 64 * j] = pk;
    }

    if (lane == 0) a_s[row] = (mag == 0.0f) ? 1.0f : (mag / 127.0f);
}

// ---------------------------------------------------------------------------
// Kernel 2: int8 GEMM, 256x128 tile, 2-deep LDS, 2 blocks/CU.
//  - cross-block overlap: while one block's waves hold the matrix pipe, the
//    co-resident block's waves do ds_read/staging/epilogue (m97 mechanism).
//  - one barrier per iter is safe: each wave drains lgkm before its MFMAs,
//    so all prior-iter ds_reads are complete before any wave passes the
//    barrier; stage writes land >=500cy after issue, well past it.
//  - stage(t+1) issued at iter top; vmcnt(0) at iter bottom => issue-to-wait
//    distance ~1 full iter (> HBM latency), plus other block covers residue.
//  - T2 swizzle (verified 0 conflicts round 3/4), T5 setprio.
// ---------------------------------------------------------------------------
__global__ __launch_bounds__(512, 4) void gemm_i8_kernel(
    const int8_t* __restrict__ A,    // [M, K]
    const int8_t* __restrict__ W,    // [N, K]
    const float* __restrict__ a_s,   // [M]
    const float* __restrict__ w_s,   // [N]
    float* __restrict__ out)         // [M, N]
{
    __shared__ __attribute__((aligned(16))) int8_t smem[2 * BUF_BYTES];

    const int t = threadIdx.x;
    const int lane = t & 63;
    const int wid = t >> 6;      // 0..7
    const int wr = wid >> 1;     // 0..3  (M quarter, 64 rows)
    const int wc = wid & 1;      // 0..1  (N half, 64 cols)

    // XCD-aware bijective swizzle (nwg = 1024, divisible by 8)
    const int bid = blockIdx.x;
    const int sbid = (bid & 7) * (gridDim.x >> 3) + (bid >> 3);
    const int ntn = N_DIM / BN;          // 16
    const int bm = sbid / ntn;           // 0..63
    const int bn = sbid % ntn;           // 0..15

    const int8_t* aSrc = A + (size_t)(bm * BM) * K_DIM;
    const int8_t* bSrc = W + (size_t)(bn * BN) * K_DIM;

    // staging: A = 1024 x 16B chunks (2/thread), B = 512 chunks (1/thread)
    const int fA0 = t, fA1 = t + 512, fB = t;
    const int rA0 = fA0 >> 2, uA0 = fA0 & 3;
    const int rA1 = fA1 >> 2, uA1 = fA1 & 3;
    const int rBs = fB >> 2,  uBs = fB & 3;
    const size_t gA0 = (size_t)rA0 * K_DIM + (size_t)((uA0 ^ ((rA0 >> 1) & 3)) << 4);
    const size_t gA1 = (size_t)rA1 * K_DIM + (size_t)((uA1 ^ ((rA1 >> 1) & 3)) << 4);
    const size_t gB0 = (size_t)rBs * K_DIM + (size_t)((uBs ^ ((rBs >> 1) & 3)) << 4);

    #define STAGE(tile)                                                                     \
    do {                                                                                    \
        int8_t* base_ = smem + ((tile) & 1) * BUF_BYTES;                                    \
        const int k0_ = (tile) * BK;                                                        \
        __builtin_amdgcn_global_load_lds(                                                   \
            (const __attribute__((address_space(1))) void*)(aSrc + k0_ + gA0),              \
            (__attribute__((address_space(3))) void*)(base_ + fA0 * 16), 16, 0, 0);         \
        __builtin_amdgcn_global_load_lds(                                                   \
            (const __attribute__((address_space(1))) void*)(aSrc + k0_ + gA1),              \
            (__attribute__((address_space(3))) void*)(base_ + fA1 * 16), 16, 0, 0);         \
        __builtin_amdgcn_global_load_lds(                                                   \
            (const __attribute__((address_space(1))) void*)(bSrc + k0_ + gB0),              \
            (__attribute__((address_space(3))) void*)(base_ + TILE_A_BYTES + fB * 16), 16, 0, 0); \
    } while (0)

    // fragment read addressing (T2-swizzled; +16 rows = +1024B keeps swz bits)
    const int frow = lane & 15;
    const int fc = lane >> 4;                       // 16B k-chunk 0..3
    const int rA = wr * 64 + frow;                  // + mf*16
    const int rB = wc * 64 + frow;                  // + nf*16
    const int aOff = rA * 64 + ((((rA >> 1) & 3) ^ fc) << 4);
    const int bOff = rB * 64 + ((((rB >> 1) & 3) ^ fc) << 4);

    v4i acc[4][4] = {};

    STAGE(0);
    asm volatile("s_waitcnt vmcnt(0)" ::: "memory");
    __builtin_amdgcn_s_barrier();
    asm volatile("" ::: "memory");

    for (int tt = 0; tt < NT; ++tt) {
        if (tt + 1 < NT) STAGE(tt + 1);   // issue early: full iter before wait

        const int8_t* Ab = smem + (tt & 1) * BUF_BYTES;
        const int8_t* Bb = Ab + TILE_A_BYTES;

        v4i af[4], bf[4];
        #pragma unroll
        for (int mf = 0; mf < 4; ++mf)
            af[mf] = *(const v4i*)(Ab + aOff + mf * 1024);
        #pragma unroll
        for (int nf = 0; nf < 4; ++nf)
            bf[nf] = *(const v4i*)(Bb + bOff + nf * 1024);

        __builtin_amdgcn_s_setprio(1);
        #pragma unroll
        for (int mf = 0; mf < 4; ++mf)
            #pragma unroll
            for (int nf = 0; nf < 4; ++nf)
                acc[mf][nf] = __builtin_amdgcn_mfma_i32_16x16x64_i8(
                    af[mf], bf[nf], acc[mf][nf], 0, 0, 0);
        __builtin_amdgcn_s_setprio(0);

        if (tt + 1 < NT) {
            asm volatile("" ::: "memory");
            asm volatile("s_waitcnt vmcnt(0)" ::: "memory");  // t+1 landed (issued 1 iter ago)
            __builtin_amdgcn_s_barrier();
            asm volatile("" ::: "memory");
        }
    }
    #undef STAGE

    // epilogue: dequant + store. C/D layout: col=lane&15, row=(lane>>4)*4+j [m89]
    const int row0 = bm * BM + wr * 64;
    const int col0 = bn * BN + wc * 64;
    #pragma unroll
    for (int mf = 0; mf < 4; ++mf) {
        const int rbase = row0 + mf * 16 + (lane >> 4) * 4;
        #pragma unroll
        for (int nf = 0; nf < 4; ++nf) {
            const int c = col0 + nf * 16 + (lane & 15);
            const float ws = w_s[c];
            #pragma unroll
            for (int j = 0; j < 4; ++j) {
                const int r = rbase + j;
                out[(size_t)r * N_DIM + c] = ((float)acc[mf][nf][j] * a_s[r]) * ws;
            }
        }
    }
}

// ---------------------------------------------------------------------------
extern "C" void kernel_launch(void* const* d_in, const int* in_sizes, int n_in,
                              void* d_out, int out_size, void* d_ws, size_t ws_size,
                              hipStream_t stream) {
    const float* x = (const float*)d_in[0];
    const int* w32 = (const int*)d_in[1];       // int8 widened to int32 by harness
    const float* wscale = (const float*)d_in[2];
    float* out = (float*)d_out;

    // workspace layout: [ q int8 M*K | a_s f32 M | w8 int8 N*K ]
    int8_t* q = (int8_t*)d_ws;
    float* a_s = (float*)((char*)d_ws + (size_t)M_DIM * K_DIM);
    int8_t* w8 = (int8_t*)((char*)d_ws + (size_t)M_DIM * K_DIM + (size_t)M_DIM * 4);

    pack_w_kernel<<<(N_DIM * K_DIM) / (256 * 8), 256, 0, stream>>>(w32, w8);
    quant_kernel<<<M_DIM / 4, 256, 0, stream>>>(x, q, a_s);

    const int grid = (M_DIM / BM) * (N_DIM / BN);   // 64 * 16 = 1024
    gemm_i8_kernel<<<grid, 512, 0, stream>>>(q, w8, a_s, wscale, out);
}